// Round 10
// baseline (725.779 us; speedup 1.0000x reference)
//
#include <hip/hip_runtime.h>

typedef _Float16 f16x8 __attribute__((ext_vector_type(8)));
typedef _Float16 f16x2 __attribute__((ext_vector_type(2)));
typedef __fp16 fp16x2_raw __attribute__((ext_vector_type(2)));
typedef float f32x4 __attribute__((ext_vector_type(4)));
typedef float f32x2 __attribute__((ext_vector_type(2)));
typedef unsigned int uint32;
typedef unsigned short ushort16;
typedef unsigned char uchar;

#define EPS_BN 1e-5f

__device__ __forceinline__ uint32 pk16(float a, float b){
  fp16x2_raw h = __builtin_amdgcn_cvt_pkrtz(a, b);
  return *(uint32*)&h;
}
__device__ __forceinline__ uchar f2fp8(float f){
  uint32 p = __builtin_amdgcn_cvt_pk_fp8_f32(f, f, 0, false);
  return (uchar)(p & 0xff);
}
__device__ __forceinline__ f32x2 fp8pair_lo(uint32 w){
  return __builtin_amdgcn_cvt_pk_f32_fp8(w, false);
}
__device__ __forceinline__ f32x2 fp8pair_hi(uint32 w){
  return __builtin_amdgcn_cvt_pk_f32_fp8(w, true);
}

// ---------------- weight conversion table ----------------
struct WEnt { const float* s; const float* s2; ushort16* d; int KD, MD, nfrag; };
struct WConv { WEnt e[16]; };

// ---------------- conv f32->f16 for h/sv ----------------
__global__ __launch_bounds__(256) void conv2_k(const float* __restrict__ a, const float* __restrict__ b,
                                               ushort16* __restrict__ da, ushort16* __restrict__ db, int n){
  const float* s = blockIdx.y ? b : a;
  ushort16* d = blockIdx.y ? db : da;
  int i = (blockIdx.x * 256 + threadIdx.x) * 4;
  if (i >= n) return;
  float4 v = *(const float4*)(s + i);
  uint2 p;
  p.x = pk16(v.x, v.y);
  p.y = pk16(v.z, v.w);
  *(uint2*)(d + i) = p;
}

// ---------------- aux: bucket-count (x<512) + conv_w (x>=512) ----------------
__global__ __launch_bounds__(256) void aux_k(WConv wc,
    const int* __restrict__ dst, int* __restrict__ bcnt, int E, int shift){
  int bx = blockIdx.x;
  if (bx < 512){
    __shared__ int lh[128];
    int tid = threadIdx.x;
    if (tid < 128) lh[tid] = 0;
    __syncthreads();
    int stride = 512 * 256;
    for (int i = bx * 256 + tid; i < E; i += stride)
      atomicAdd(&lh[dst[i] >> shift], 1);
    __syncthreads();
    if (tid < 128 && lh[tid]) atomicAdd(&bcnt[tid], lh[tid]);
  } else {
    int b = bx - 512;
    WEnt t = wc.e[b >> 4];
    int fid = (b & 15) * 256 + threadIdx.x;
    if (fid >= t.nfrag) return;
    int lane = fid & 63, sm = fid >> 6;
    int MT = t.MD >> 4;
    int s = sm / MT, m = sm - s * MT;
    int row = m * 16 + (lane & 15);
    int col = s * 32 + (lane >> 4) * 8;
    const float* sp = t.s;
    if (t.s2 && row >= 128){ sp = t.s2; row -= 128; }
    const float* p = sp + (size_t)row * t.KD + col;
    uint4 o;
    o.x = pk16(p[0], p[1]); o.y = pk16(p[2], p[3]);
    o.z = pk16(p[4], p[5]); o.w = pk16(p[6], p[7]);
    *(uint4*)(t.d + (size_t)fid * 8) = o;
  }
}

// ---------------- bucket prefix (tiny) ----------------
__global__ __launch_bounds__(64) void bscan_k(const int* __restrict__ bcnt,
    int* __restrict__ bstart, int* __restrict__ bcur, int B){
  if (threadIdx.x == 0){
    int run = 0;
    for (int b = 0; b < B; b++){ bstart[b] = run; bcur[b] = run; run += bcnt[b]; }
    bstart[B] = run;
  }
}

// ---------------- bucketed grouping: LDS-binned by dst bucket ----------------
#define BIN_TB 512
#define BIN_TILE 4096
__global__ __launch_bounds__(512) void bin_k(const int* __restrict__ src, const int* __restrict__ dst,
                                             int* __restrict__ bcur, uint2* __restrict__ ebuf,
                                             int E, int shift, int B){
  __shared__ int lhist[128];
  __shared__ int lstart[128];
  __shared__ int gbase[128];
  __shared__ uint2 lpair[BIN_TILE];
  int tid = threadIdx.x;
  int base = blockIdx.x * BIN_TILE;
  int cnt = E - base; if (cnt > BIN_TILE) cnt = BIN_TILE;
  if (tid < 128) lhist[tid] = 0;
  __syncthreads();
  int myb[8], myrank[8];
  uint2 myp[8];
  int nmine = 0;
  #pragma unroll
  for (int j = 0; j < 8; j++){
    int i = tid + j * BIN_TB;
    if (i < cnt){
      int s = src[base + i], d = dst[base + i];
      int b = d >> shift;
      myp[nmine] = make_uint2((uint32)s, (uint32)d);
      myb[nmine] = b;
      myrank[nmine] = atomicAdd(&lhist[b], 1);
      nmine++;
    }
  }
  __syncthreads();
  if (tid == 0){
    int run = 0;
    for (int b = 0; b < B; b++){ lstart[b] = run; run += lhist[b]; }
  }
  __syncthreads();
  if (tid < B) gbase[tid] = atomicAdd(&bcur[tid], lhist[tid]);
  for (int j = 0; j < nmine; j++){
    lpair[lstart[myb[j]] + myrank[j]] = myp[j];
  }
  __syncthreads();
  for (int i = tid; i < cnt; i += BIN_TB){
    uint2 p = lpair[i];
    int b = (int)(p.y >> shift);
    ebuf[gbase[b] + (i - lstart[b])] = p;
  }
}

// ---------------- per-bucket CSR finalize: row_off + esrc, LDS-atomic only ----------------
#define CSR_TB 1024
__global__ __launch_bounds__(1024) void csr_k(const uint2* __restrict__ ebuf,
    const int* __restrict__ bstart, int* __restrict__ row_off, int* __restrict__ esrc,
    int shift, int N, int E, int B){
  __shared__ int lc[4096];
  __shared__ int lcur[4096];
  __shared__ int wsum[16];
  int b = blockIdx.x;
  int d0 = b << shift;
  int nd = 1 << shift; if (d0 + nd > N) nd = N - d0;
  if (nd <= 0) return;
  int e0 = bstart[b], e1 = bstart[b + 1];
  int tid = threadIdx.x, lane = tid & 63, wv = tid >> 6;
  for (int j = tid; j < nd; j += CSR_TB){ lc[j] = 0; lcur[j] = 0; }
  __syncthreads();
  // pass 1: per-dst counts (LDS atomics)
  for (int i = e0 + tid; i < e1; i += CSR_TB){
    atomicAdd(&lc[(int)ebuf[i].y - d0], 1);
  }
  __syncthreads();
  // block exclusive scan of lc[0..nd), 4 elements per thread
  int base4 = tid * 4;
  int v0 = (base4 + 0 < nd) ? lc[base4 + 0] : 0;
  int v1 = (base4 + 1 < nd) ? lc[base4 + 1] : 0;
  int v2 = (base4 + 2 < nd) ? lc[base4 + 2] : 0;
  int v3 = (base4 + 3 < nd) ? lc[base4 + 3] : 0;
  int ts = v0 + v1 + v2 + v3;
  int inc = ts;
  #pragma unroll
  for (int d = 1; d < 64; d <<= 1){
    int t = __shfl_up(inc, d);
    if (lane >= d) inc += t;
  }
  if (lane == 63) wsum[wv] = inc;
  __syncthreads();
  int woff = 0;
  for (int w = 0; w < 16; w++) if (w < wv) woff += wsum[w];
  int excl = woff + (inc - ts);
  int o0 = excl, o1 = o0 + v0, o2 = o1 + v1, o3 = o2 + v2;
  __syncthreads();   // all reads of lc done before overwrite
  if (base4 + 0 < nd){ lc[base4 + 0] = o0; row_off[d0 + base4 + 0] = e0 + o0; }
  if (base4 + 1 < nd){ lc[base4 + 1] = o1; row_off[d0 + base4 + 1] = e0 + o1; }
  if (base4 + 2 < nd){ lc[base4 + 2] = o2; row_off[d0 + base4 + 2] = e0 + o2; }
  if (base4 + 3 < nd){ lc[base4 + 3] = o3; row_off[d0 + base4 + 3] = e0 + o3; }
  __syncthreads();
  // pass 2: rank-scatter esrc (LDS cursor atomics only)
  for (int i = e0 + tid; i < e1; i += CSR_TB){
    uint2 p = ebuf[i];
    int d = (int)p.y - d0;
    int r = atomicAdd(&lcur[d], 1);
    esrc[e0 + lc[d] + r] = (int)p.x;
  }
  if (b == B - 1 && tid == 0) row_off[N] = E;
}

// ---------------- generic GEMM body, swizzled W, f16 in/out, LDS-staged stores ----------------
// EPI: 1=relu, 2=sigmoid, 3=+res(f16), 4=gate w/ res(f16), 5=+BN(res), 6=gate w/ BN(res)
template<int KD, int MD, int EPI, int ABN, int ST, int GS>
__device__ __forceinline__ void gemm_body(
    const ushort16* __restrict__ X, const ushort16* __restrict__ W,
    const float* __restrict__ bias, const float* __restrict__ bias2,
    const ushort16* __restrict__ resb, const ushort16* __restrict__ gatep,
    const float* __restrict__ rstats, const float* __restrict__ rg, const float* __restrict__ rb,
    const float* __restrict__ astats, const float* __restrict__ ag, const float* __restrict__ ab,
    ushort16* __restrict__ outb, float* __restrict__ stats_out, int N, float invN,
    _Float16* OsBase, float* sstB, float* sst2B)
{
  constexpr int KS = KD / 32;
  constexpr int MT = MD / 16;
  constexpr int LSTR = MD + 8;
  int lane = threadIdx.x & 63, wv = threadIdx.x >> 6;
  _Float16* OsW = OsBase + wv * 16 * LSTR;
  int l15 = lane & 15, kq = lane >> 4;
  int rowbase = (blockIdx.x * 4 + wv) * 16;
  int row = rowbase + l15;
  int rc = row < N ? row : N - 1;
  const f16x8* ap = (const f16x8*)(X + (size_t)rc * KD + kq * 8);
  f16x8 a[KS];
  #pragma unroll
  for (int s = 0; s < KS; s++) a[s] = ap[s * 4];
  if constexpr (ABN){
    #pragma unroll
    for (int s = 0; s < KS; s++){
      #pragma unroll
      for (int j = 0; j < 8; j++){
        int c = s * 32 + kq * 8 + j;
        float mm = astats[c] * invN;
        float var = astats[128 + c] * invN - mm * mm;
        float rs = rsqrtf(var + EPS_BN);
        float scc = rs * ag[c];
        float shh = ab[c] - mm * scc;
        a[s][j] = (_Float16)((float)a[s][j] * scc + shh);
      }
    }
  }
  const f16x8* Wf = (const f16x8*)W;
  f32x4 acc[MT];
  #pragma unroll
  for (int m = 0; m < MT; m++) acc[m] = (f32x4)(0.f);
  #pragma unroll
  for (int s = 0; s < KS; s++){
    #pragma unroll
    for (int m = 0; m < MT; m++){
      acc[m] = __builtin_amdgcn_mfma_f32_16x16x32_f16(a[s], Wf[(s * MT + m) * 64 + lane], acc[m], 0, 0, 0);
    }
  }
  float ps[MT], ps2[MT];
  if constexpr (ST){
    #pragma unroll
    for (int m = 0; m < MT; m++){ ps[m] = 0.f; ps2[m] = 0.f; }
  }
  int r0 = rowbase + kq * 4;
  #pragma unroll
  for (int m = 0; m < MT; m++){
    int col = m * 16 + l15;
    float bv;
    if (bias2 && col >= 128) bv = bias2[col - 128];
    else bv = bias[col];
    float sc = 0.f, sh = 0.f;
    if constexpr (EPI == 5 || EPI == 6){
      float mm = rstats[col] * invN;
      float var = rstats[128 + col] * invN - mm * mm;
      float rs = rsqrtf(var + EPS_BN);
      sc = rs * rg[col]; sh = rb[col] - mm * sc;
    }
    #pragma unroll
    for (int r = 0; r < 4; r++){
      int rr = r0 + r;
      float v;
      {
        int rrc = rr < N ? rr : N - 1;
        v = acc[m][r] + bv;
        if constexpr (EPI == 1) v = fmaxf(v, 0.f);
        if constexpr (EPI == 2) v = 1.f / (1.f + __expf(-v));
        if constexpr (EPI == 3){
          union { ushort16 u; _Float16 h; } cv; cv.u = resb[(size_t)rrc * 128 + col];
          v += (float)cv.h;
        }
        if constexpr (EPI == 5){
          union { ushort16 u; _Float16 h; } cv; cv.u = resb[(size_t)rrc * 128 + col];
          v += (float)cv.h * sc + sh;
        }
        if constexpr (EPI == 4 || EPI == 6){
          union { ushort16 u; _Float16 h; } gv; gv.u = gatep[(size_t)rrc * GS + col];
          union { ushort16 u; _Float16 h; } cv; cv.u = resb[(size_t)rrc * 128 + col];
          float g = (float)gv.h;
          float rv = (float)cv.h;
          if constexpr (EPI == 6) rv = rv * sc + sh;
          v = (1.f - g) * rv + g * v;
        }
      }
      OsW[(kq * 4 + r) * LSTR + col] = (_Float16)v;
      if constexpr (ST){
        if (rr < N){ ps[m] += v; ps2[m] += v * v; }
      }
    }
  }
  if constexpr (MD == 128){
    #pragma unroll
    for (int p = 0; p < 4; p++){
      int lrow = p * 4 + (lane >> 4);
      int rr = rowbase + lrow;
      int col8 = l15 * 8;
      if (rr < N){
        uint4 ov = *(uint4*)&OsW[lrow * LSTR + col8];
        *(uint4*)(outb + (size_t)rr * MD + col8) = ov;
      }
    }
  } else {
    #pragma unroll
    for (int p = 0; p < 8; p++){
      int lrow = p * 2 + (lane >> 5);
      int rr = rowbase + lrow;
      int col8 = (lane & 31) * 8;
      if (rr < N){
        uint4 ov = *(uint4*)&OsW[lrow * LSTR + col8];
        *(uint4*)(outb + (size_t)rr * MD + col8) = ov;
      }
    }
  }
  if constexpr (ST){
    #pragma unroll
    for (int m = 0; m < MT; m++){
      float s = ps[m], s2 = ps2[m];
      s  += __shfl_xor(s, 16);  s  += __shfl_xor(s, 32);
      s2 += __shfl_xor(s2, 16); s2 += __shfl_xor(s2, 32);
      if (lane < 16){ sstB[wv * 128 + m * 16 + l15] = s; sst2B[wv * 128 + m * 16 + l15] = s2; }
    }
    __syncthreads();
    int tid = threadIdx.x;
    if (tid < 128){
      atomicAdd(&stats_out[tid], sstB[tid] + sstB[128 + tid] + sstB[256 + tid] + sstB[384 + tid]);
    } else {
      int c = tid - 128;
      atomicAdd(&stats_out[tid], sst2B[c] + sst2B[128 + c] + sst2B[256 + c] + sst2B[384 + c]);
    }
  }
}

// single-config GEMM kernel (used for the gate projection)
template<int KD, int MD, int EPI, int ABN, int ST, int GS>
__global__ __launch_bounds__(256) void gemm_k(
    const ushort16* __restrict__ X, const ushort16* __restrict__ W,
    const float* __restrict__ bias, const float* __restrict__ bias2,
    const ushort16* __restrict__ resb, const ushort16* __restrict__ gatep,
    const float* __restrict__ rstats, const float* __restrict__ rg, const float* __restrict__ rb,
    const float* __restrict__ astats, const float* __restrict__ ag, const float* __restrict__ ab,
    ushort16* __restrict__ outb, float* __restrict__ stats_out, int N, float invN)
{
  __shared__ _Float16 Os[4 * 16 * (MD + 8)];
  __shared__ float sst[512];
  __shared__ float sst2[512];
  gemm_body<KD, MD, EPI, ABN, ST, GS>(X, W, bias, bias2, resb, gatep, rstats, rg, rb,
                                      astats, ag, ab, outb, stats_out, N, invN, Os, sst, sst2);
}

// ---------------- QKV projection x4 slots: block-level LDS weight staging ----------------
// Each block stages Wq -> LDS once (vs once PER WAVE from L2 before: 4x traffic cut),
// computes Q for its 64 rows from LDS, then repeats for Wk, Wv.
struct QkvArgs {
  const ushort16* Xq[4];
  const ushort16* Xkv[4];
  const ushort16* Wq[4];
  const ushort16* Wk[4];
  const ushort16* Wv[4];
  ushort16* Qo[4];
};
__global__ __launch_bounds__(256) void qkv_k(QkvArgs A, uchar* __restrict__ KV8, int N)
{
  __shared__ _Float16 Wl[16384];        // 32 KB staged weight matrix
  __shared__ _Float16 S[4][16 * 136];   // 17.4 KB per-wave stage-out
  int slot = blockIdx.y;
  int toff = slot << 8;
  const ushort16* Xq = A.Xq[slot];
  const ushort16* Xkv = A.Xkv[slot];
  ushort16* Qo = A.Qo[slot];
  int tid = threadIdx.x;
  int lane = tid & 63, wv = tid >> 6;
  _Float16* SW = S[wv];
  uchar* SB = (uchar*)SW;
  int l15 = lane & 15, kq = lane >> 4;
  int rowbase = (blockIdx.x * 4 + wv) * 16;
  int row = rowbase + l15;
  int rc = row < N ? row : N - 1;
  const f16x8* aq = (const f16x8*)(Xq + (size_t)rc * 128 + kq * 8);
  const f16x8* ak = (const f16x8*)(Xkv + (size_t)rc * 128 + kq * 8);
  f16x8 Aq[4], Ak[4];
  #pragma unroll
  for (int s = 0; s < 4; s++){ Aq[s] = aq[s * 4]; Ak[s] = ak[s * 4]; }
  const uint4* Wq4 = (const uint4*)A.Wq[slot];
  const uint4* Wk4 = (const uint4*)A.Wk[slot];
  const uint4* Wv4 = (const uint4*)A.Wv[slot];
  uint4* Wl4 = (uint4*)Wl;
  const f16x8* Wl8 = (const f16x8*)Wl;
  f32x4 acc[8];

  // ---- stage Q ----
  {
    uint4 wb[8];
    #pragma unroll
    for (int r = 0; r < 8; r++) wb[r] = Wq4[tid + r * 256];
    #pragma unroll
    for (int r = 0; r < 8; r++) Wl4[tid + r * 256] = wb[r];
  }
  __syncthreads();
  #pragma unroll
  for (int m = 0; m < 8; m++) acc[m] = (f32x4)(0.f);
  #pragma unroll
  for (int s = 0; s < 4; s++){
    #pragma unroll
    for (int m = 0; m < 8; m++){
      acc[m] = __builtin_amdgcn_mfma_f32_16x16x32_f16(Aq[s], Wl8[(s * 8 + m) * 64 + lane], acc[m], 0, 0, 0);
    }
  }
  #pragma unroll
  for (int m = 0; m < 8; m++){
    int col = m * 16 + l15;
    #pragma unroll
    for (int r = 0; r < 4; r++)
      SW[(kq * 4 + r) * 136 + col] = (_Float16)acc[m][r];
  }
  #pragma unroll
  for (int p = 0; p < 4; p++){
    int lrow = p * 4 + kq;
    int rr = rowbase + lrow;
    int col8 = l15 * 8;
    if (rr < N){
      uint4 qv = *(uint4*)&SW[lrow * 136 + col8];
      *(uint4*)(Qo + (size_t)rr * 128 + col8) = qv;
    }
  }
  __syncthreads();   // all waves done reading Wl before overwrite

  // ---- stage K ----
  {
    uint4 wb[8];
    #pragma unroll
    for (int r = 0; r < 8; r++) wb[r] = Wk4[tid + r * 256];
    #pragma unroll
    for (int r = 0; r < 8; r++) Wl4[tid + r * 256] = wb[r];
  }
  __syncthreads();
  #pragma unroll
  for (int m = 0; m < 8; m++) acc[m] = (f32x4)(0.f);
  #pragma unroll
  for (int s = 0; s < 4; s++){
    #pragma unroll
    for (int m = 0; m < 8; m++){
      acc[m] = __builtin_amdgcn_mfma_f32_16x16x32_f16(Ak[s], Wl8[(s * 8 + m) * 64 + lane], acc[m], 0, 0, 0);
    }
  }
  #pragma unroll
  for (int m = 0; m < 8; m++){
    int col = m * 16 + l15;
    #pragma unroll
    for (int r = 0; r < 4; r++)
      SB[(kq * 4 + r) * 136 + col] = f2fp8(acc[m][r]);
  }
  #pragma unroll
  for (int p = 0; p < 4; p++){
    int lrow = p * 4 + kq;
    int rr = rowbase + lrow;
    int col8 = l15 * 8;
    if (rr < N){
      uint2 kv = *(uint2*)&SB[lrow * 136 + col8];
      *(uint2*)(KV8 + (size_t)rr * 1024 + toff + col8) = kv;
    }
  }
  __syncthreads();

  // ---- stage V ----
  {
    uint4 wb[8];
    #pragma unroll
    for (int r = 0; r < 8; r++) wb[r] = Wv4[tid + r * 256];
    #pragma unroll
    for (int r = 0; r < 8; r++) Wl4[tid + r * 256] = wb[r];
  }
  __syncthreads();
  #pragma unroll
  for (int m = 0; m < 8; m++) acc[m] = (f32x4)(0.f);
  #pragma unroll
  for (int s = 0; s < 4; s++){
    #pragma unroll
    for (int m = 0; m < 8; m++){
      acc[m] = __builtin_amdgcn_mfma_f32_16x16x32_f16(Ak[s], Wl8[(s * 8 + m) * 64 + lane], acc[m], 0, 0, 0);
    }
  }
  #pragma unroll
  for (int m = 0; m < 8; m++){
    int col = m * 16 + l15;
    #pragma unroll
    for (int r = 0; r < 4; r++)
      SB[(kq * 4 + r) * 136 + col] = f2fp8(acc[m][r]);
  }
  #pragma unroll
  for (int p = 0; p < 4; p++){
    int lrow = p * 4 + kq;
    int rr = rowbase + lrow;
    int col8 = l15 * 8;
    if (rr < N){
      uint2 vv = *(uint2*)&SB[lrow * 136 + col8];
      *(uint2*)(KV8 + (size_t)rr * 1024 + toff + 128 + col8) = vv;
    }
  }
}

// paired GEMM kernel: blockIdx.y selects config (h-branch / sv-branch), shapes identical
struct GPairArgs {
  const ushort16* X[2]; const ushort16* W[2];
  const float* bias[2];
  const ushort16* resb[2]; const ushort16* gatep[2];
  const float* rstats[2]; const float* rg[2]; const float* rb[2];
  const float* astats[2]; const float* ag[2]; const float* ab[2];
  ushort16* outb[2]; float* stats_out[2];
};
template<int KD, int MD, int EPI0, int EPI1, int ABN, int ST, int GS>
__global__ __launch_bounds__(256) void gemm_pair_k(GPairArgs A, int N, float invN)
{
  __shared__ _Float16 Os[4 * 16 * (MD + 8)];
  __shared__ float sst[512];
  __shared__ float sst2[512];
  int y = blockIdx.y;
  if (y == 0){
    gemm_body<KD, MD, EPI0, ABN, ST, GS>(A.X[0], A.W[0], A.bias[0], nullptr, A.resb[0], A.gatep[0],
        A.rstats[0], A.rg[0], A.rb[0], A.astats[0], A.ag[0], A.ab[0],
        A.outb[0], A.stats_out[0], N, invN, Os, sst, sst2);
  } else {
    gemm_body<KD, MD, EPI1, ABN, ST, GS>(A.X[1], A.W[1], A.bias[1], nullptr, A.resb[1], A.gatep[1],
        A.rstats[1], A.rg[1], A.rb[1], A.astats[1], A.ag[1], A.ab[1],
        A.outb[1], A.stats_out[1], N, invN, Os, sst, sst2);
  }
}

// ---------------- fused QUAD attention, 16 lanes/edge, interleaved KV pool ----------------
// BW-walled on the random-gather path (~3.8 TB/s); frozen since r3.
// Range-dispatched [n0,n1): 3 slices this round for rest-pool visibility.
__global__ __launch_bounds__(256) void attn4_k(
    const ushort16* __restrict__ Qa, const ushort16* __restrict__ Qb,
    const ushort16* __restrict__ Qc, const ushort16* __restrict__ Qd,
    const uchar* __restrict__ KV,
    const int* __restrict__ row_off, const int* __restrict__ esrc,
    ushort16* __restrict__ cat_h, ushort16* __restrict__ cat_sv, int n0, int n1)
{
  int wv = threadIdx.x >> 6, lane = threadIdx.x & 63;
  int n = n0 + blockIdx.x * 4 + wv;
  if (n >= n1) return;
  int g = lane >> 4, j = lane & 15;      // 4 edge slots x 16 lanes
  uint32 j8 = (uint32)j * 8u;            // 8 fp8 elems per lane
  const float QS = 0.25f * 1.44269504088896f; // 1/sqrt(DH) * log2(e)
  const float CL = 7.21347520444482f;          // 5 * log2(e)
  const ushort16* Qp[4] = {Qa, Qb, Qc, Qd};
  f32x2 q[4][4];
  #pragma unroll
  for (int t = 0; t < 4; t++){
    uint4 u = *(const uint4*)(Qp[t] + (size_t)n * 128 + j8);
    f16x2 h0 = *(f16x2*)&u.x, h1 = *(f16x2*)&u.y;
    f16x2 h2 = *(f16x2*)&u.z, h3 = *(f16x2*)&u.w;
    q[t][0].x = (float)h0.x * QS; q[t][0].y = (float)h0.y * QS;
    q[t][1].x = (float)h1.x * QS; q[t][1].y = (float)h1.y * QS;
    q[t][2].x = (float)h2.x * QS; q[t][2].y = (float)h2.y * QS;
    q[t][3].x = (float)h3.x * QS; q[t][3].y = (float)h3.y * QS;
  }
  int e0 = row_off[n], e1 = row_off[n + 1];
  int itmax = (e1 - e0 + 3) >> 2;
  f32x2 ac[4][4];
  #pragma unroll
  for (int t = 0; t < 4; t++){
    #pragma unroll
    for (int r = 0; r < 4; r++) ac[t][r] = (f32x2)(0.f);
  }
  float z[4] = {0.f, 0.f, 0.f, 0.f};
  int e = e0 + g;
  int s = (e < e1) ? esrc[e] : -1;
  uint32 off = ((uint32)(s < 0 ? 0 : s) << 10) + j8;
  uint2 kc[4], vc[4];
  #pragma unroll
  for (int t = 0; t < 4; t++){
    kc[t] = *(const uint2*)(KV + off + t * 256);
    vc[t] = *(const uint2*)(KV + off + t * 256 + 128);
  }
  for (int it = 0; it < itmax; ++it){
    int e2 = e + 4;
    int s2 = (e2 < e1) ? esrc[e2] : -1;
    uint32 off2 = ((uint32)(s2 < 0 ? 0 : s2) << 10) + j8;
    uint2 kn[4], vn[4];
    #pragma unroll
    for (int t = 0; t < 4; t++){
      kn[t] = *(const uint2*)(KV + off2 + t * 256);
      vn[t] = *(const uint2*)(KV + off2 + t * 256 + 128);
    }
    if (s >= 0){
      #pragma unroll
      for (int t = 0; t < 4; t++){
        f32x2 k0 = fp8pair_lo(kc[t].x), k1 = fp8pair_hi(kc[t].x);
        f32x2 k2 = fp8pair_lo(kc[t].y), k3 = fp8pair_hi(kc[t].y);
        f32x2 dd = k0 * q[t][0] + k1 * q[t][1] + k2 * q[t][2] + k3 * q[t][3];
        float d = dd.x + dd.y;
        d += __shfl_xor(d, 1);   // lanes j, j^1 cover one 16-elem head
        float sc = __builtin_amdgcn_exp2f(__builtin_amdgcn_fmed3f(d, -CL, CL));
        f32x2 v0 = fp8pair_lo(vc[t].x), v1 = fp8pair_hi(vc[t].x);
        f32x2 v2 = fp8pair_lo(vc[t].y), v3 = fp8pair_hi(vc[t].y);
        f32x2 sv; sv.x = sc; sv.y = sc;
        ac[t][0] += sv * v0; ac[t][1] += sv * v1;
        ac[t][2] += sv * v2; ac[t][3] += sv * v3;
        z[t] += sc;
      }
    }
    e = e2; s = s2; off = off2;
    #pragma unroll
    for (int t = 0; t < 4; t++){ kc[t] = kn[t]; vc[t] = vn[t]; }
  }
  // reduce across the 4 edge slots (lanes differing in bits 4,5)
  #pragma unroll
  for (int t = 0; t < 4; t++){
    #pragma unroll
    for (int r = 0; r < 4; r++){
      ac[t][r].x += __shfl_xor(ac[t][r].x, 16);
      ac[t][r].y += __shfl_xor(ac[t][r].y, 16);
      ac[t][r].x += __shfl_xor(ac[t][r].x, 32);
      ac[t][r].y += __shfl_xor(ac[t][r].y, 32);
    }
    z[t] += __shfl_xor(z[t], 16);
    z[t] += __shfl_xor(z[t], 32);
  }
  if (g == 0){
    size_t base = (size_t)n * 256 + j8;
    #pragma unroll
    for (int t = 0; t < 4; t++){
      float rz = __builtin_amdgcn_rcpf(z[t]);
      uint4 o;
      o.x = pk16(ac[t][0].x * rz, ac[t][0].y * rz);
      o.y = pk16(ac[t][1].x * rz, ac[t][1].y * rz);
      o.z = pk16(ac[t][2].x * rz, ac[t][2].y * rz);
      o.w = pk16(ac[t][3].x * rz, ac[t][3].y * rz);
      ushort16* dp = (t < 2) ? cat_h : cat_sv;
      *(uint4*)(dp + base + (t & 1) * 128) = o;
    }
  }
}

// ---------------- BatchNorm apply pair (f16 in, f32 out) ----------------
struct Bn2Args {
  const ushort16* x[2]; const float* stats[2];
  const float* g[2]; const float* b[2]; float* out[2];
};
__global__ __launch_bounds__(256) void bn2_k(Bn2Args A, int total4, float invN)
{
  int y = blockIdx.y;
  int i = blockIdx.x * 256 + threadIdx.x;
  if (i >= total4) return;
  const ushort16* x = A.x[y];
  const float* stats = A.stats[y];
  const float* gamma = A.g[y];
  const float* beta = A.b[y];
  float* outf = A.out[y];
  uint2 xp = *(const uint2*)(x + (size_t)i * 4);
  f16x2 x01 = *(f16x2*)&xp.x, x23 = *(f16x2*)&xp.y;
  float xv[4] = {(float)x01.x, (float)x01.y, (float)x23.x, (float)x23.y};
  int c0 = (i * 4) & 127;
  float o[4];
  #pragma unroll
  for (int j = 0; j < 4; j++){
    int c = c0 + j;
    float m = stats[c] * invN;
    float var = stats[128 + c] * invN - m * m;
    float rstd = rsqrtf(var + EPS_BN);
    o[j] = (xv[j] - m) * rstd * gamma[c] + beta[c];
  }
  *(float4*)(outf + (size_t)i * 4) = make_float4(o[0], o[1], o[2], o[3]);
}

// ---------------- host ----------------
extern "C" void kernel_launch(void* const* d_in, const int* in_sizes, int n_in,
                              void* d_out, int out_size, void* d_ws, size_t ws_size,
                              hipStream_t stream) {
  const float* h   = (const float*)d_in[0];
  const float* sv  = (const float*)d_in[1];
  const int* src   = (const int*)d_in[2];
  const int* dst   = (const int*)d_in[3];
  const int N = in_sizes[0] / 128;
  const int E = in_sizes[2];

  char* wsb = (char*)d_ws;
  size_t o = 0;
  auto take = [&](size_t bytes)->size_t{
    size_t r = o;
    o = (o + bytes + 255) & ~(size_t)255;
    return r;
  };
  // shared big region: ebuf (CSR build) -> KV pool (attention)
  size_t big = (size_t)E * 8;
  if (big < (size_t)N * 1024) big = (size_t)N * 1024;
  size_t bcnt_off   = take(128 * 4);             // zeroed
  size_t stats_off  = take(4 * 256 * 4);         // zeroed
  size_t bstart_off = take(132 * 4);
  size_t bcur_off   = take(128 * 4);
  size_t rowoff_off = take((size_t)(N + 1) * 4);
  size_t esrc_off   = take((size_t)E * 4);
  size_t big_off    = take(big);
  size_t wpool_off  = take((size_t)376832 * 2);
  size_t hf_off     = take((size_t)N * 128 * 2);
  size_t svf_off    = take((size_t)N * 128 * 2);
  size_t cath_off   = take((size_t)N * 256 * 2);
  size_t catsv_off  = take((size_t)N * 256 * 2);
  size_t Q1_off     = take((size_t)N * 128 * 2);
  size_t Q2_off     = take((size_t)N * 128 * 2);
  size_t X1_off     = take((size_t)N * 128 * 2);
  size_t X2_off     = take((size_t)N * 128 * 2);
  size_t G_off      = take((size_t)N * 256 * 2);   // dedicated gate buffer (pre-attn)

  int*    bcnt    = (int*)(wsb + bcnt_off);
  float*  stats   = (float*)(wsb + stats_off);
  int*    bstart  = (int*)(wsb + bstart_off);
  int*    bcur    = (int*)(wsb + bcur_off);
  int*    row_off = (int*)(wsb + rowoff_off);
  int*    esrc    = (int*)(wsb + esrc_off);
  uint2*  ebuf    = (uint2*)(wsb + big_off);     // dead after csr_k
  uchar*  KVall   = (uchar*)(wsb + big_off);     // live qkv..attn4
  ushort16* wpool = (ushort16*)(wsb + wpool_off);
  ushort16* h_f   = (ushort16*)(wsb + hf_off);
  ushort16* sv_f  = (ushort16*)(wsb + svf_off);
  ushort16* cat_h = (ushort16*)(wsb + cath_off);
  ushort16* cat_sv= (ushort16*)(wsb + catsv_off);
  ushort16* Q1    = (ushort16*)(wsb + Q1_off);
  ushort16* Q2    = (ushort16*)(wsb + Q2_off);
  ushort16* Xb1   = (ushort16*)(wsb + X1_off);
  ushort16* Xb2   = (ushort16*)(wsb + X2_off);
  ushort16* Gbuf  = (ushort16*)(wsb + G_off);
  ushort16* Q3 = Xb1;                     // X1/X2 written only after attention
  ushort16* Q4 = Xb2;

  ushort16* Wq_sv = wpool + 0 * 16384;
  ushort16* Wk_sv = wpool + 1 * 16384;
  ushort16* Wv_sv = wpool + 2 * 16384;
  ushort16* Wq_cv = wpool + 3 * 16384;
  ushort16* Wk_cv = wpool + 4 * 16384;
  ushort16* Wv_cv = wpool + 5 * 16384;
  ushort16* Wq_sh = wpool + 6 * 16384;
  ushort16* Wk_sh = wpool + 7 * 16384;
  ushort16* Wv_sh = wpool + 8 * 16384;
  ushort16* Wgb   = wpool + 147456;
  ushort16* Wob   = wpool + 180224;
  ushort16* Wohb  = wpool + 212992;
  ushort16* W1b   = wpool + 245760;
  ushort16* W2b   = wpool + 278528;
  ushort16* W1hb  = wpool + 311296;
  ushort16* W2hb  = wpool + 344064;

  const float* bo   = (const float*)d_in[14];
  const float* bo_h = (const float*)d_in[16];
  const float* b1   = (const float*)d_in[18];
  const float* b2   = (const float*)d_in[20];
  const float* b1h  = (const float*)d_in[22];
  const float* b2h  = (const float*)d_in[24];
  const float* bg1  = (const float*)d_in[26];
  const float* bg2  = (const float*)d_in[28];
  const float* gbn1  = (const float*)d_in[29];
  const float* bbn1  = (const float*)d_in[30];
  const float* gbn2  = (const float*)d_in[31];
  const float* bbn2  = (const float*)d_in[32];
  const float* gbn1h = (const float*)d_in[33];
  const float* bbn1h = (const float*)d_in[34];
  const float* gbn2h = (const float*)d_in[35];
  const float* bbn2h = (const float*)d_in[36];

  float* out_h  = (float*)d_out;
  float* out_sv = out_h + (size_t)N * 128;

  (void)hipMemsetAsync(wsb, 0, stats_off + 4 * 256 * 4, stream);

  WConv wc;
  {
    auto set = [&](int i, int din, int din2, size_t dstoff, int KD, int MD){
      wc.e[i].s  = (const float*)d_in[din];
      wc.e[i].s2 = (din2 >= 0) ? (const float*)d_in[din2] : nullptr;
      wc.e[i].d  = wpool + dstoff;
      wc.e[i].KD = KD; wc.e[i].MD = MD;
      wc.e[i].nfrag = KD * MD / 8;
    };
    for (int i = 0; i < 9; i++) set(i, 4 + i, -1, (size_t)i * 16384, 128, 128);
    set(9,  25, 27, 147456, 128, 256);
    set(10, 13, -1, 180224, 256, 128);
    set(11, 15, -1, 212992, 256, 128);
    set(12, 17, -1, 245760, 128, 256);
    set(13, 19, -1, 278528, 256, 128);
    set(14, 21, -1, 311296, 128, 256);
    set(15, 23, -1, 344064, 256, 128);
  }

  // bucket params: B <= 128 buckets of 2^shift dst values
  int shift = 9;
  while ((((N - 1) >> shift) + 1) > 128) shift++;
  const int B = ((N - 1) >> shift) + 1;

  int nelem = N * 128;
  int CVB = (nelem / 4 + 255) / 256;
  // conv h/sv (right-sized) + aux (bucket-count 512 blocks, conv_w 256 blocks)
  conv2_k<<<dim3(CVB, 2), 256, 0, stream>>>(h, sv, h_f, sv_f, nelem);
  aux_k<<<768, 256, 0, stream>>>(wc, dst, bcnt, E, shift);

  bscan_k<<<1, 64, 0, stream>>>(bcnt, bstart, bcur, B);
  bin_k<<<(E + BIN_TILE - 1) / BIN_TILE, BIN_TB, 0, stream>>>(src, dst, bcur, ebuf, E, shift, B);
  csr_k<<<B, CSR_TB, 0, stream>>>(ebuf, bstart, row_off, esrc, shift, N, E, B);

  const int GB = (N + 63) / 64;
  const int T4 = nelem / 4;
  const int APB = (T4 + 255) / 256;
  const float invN = 1.f / (float)N;

  // gate projection (own dispatch)
  gemm_k<128,256,2,0,0,256><<<GB, 256, 0, stream>>>(h_f, Wgb, bg1, bg2, nullptr, nullptr,
      nullptr, nullptr, nullptr, nullptr, nullptr, nullptr, Gbuf, nullptr, N, invN);

  // four QKV projections (LDS-staged weights), then attention in 3 slices
  QkvArgs qa;
  qa.Xq[0] = h_f;  qa.Xkv[0] = h_f;  qa.Wq[0] = Wq_sv; qa.Wk[0] = Wk_sv; qa.Wv[0] = Wv_sv; qa.Qo[0] = Q1;
  qa.Xq[1] = h_f;  qa.Xkv[1] = sv_f; qa.Wq[1] = Wq_cv; qa.Wk[1] = Wk_cv; qa.Wv[1] = Wv_cv; qa.Qo[1] = Q2;
  qa.Xq[2] = sv_f; qa.Xkv[2] = sv_f; qa.Wq[2] = Wq_sh; qa.Wk[2] = Wk_sh; qa.Wv[2] = Wv_sh; qa.Qo[2] = Q3;
  qa.Xq[3] = sv_f; qa.Xkv[3] = h_f;  qa.Wq[3] = Wq_cv; qa.Wk[3] = Wk_cv; qa.Wv[3] = Wv_cv; qa.Qo[3] = Q4;
  qkv_k<<<dim3(GB, 4), 256, 0, stream>>>(qa, KVall, N);

  {
    int per = ((N + 2) / 3 + 3) & ~3;
    for (int n0 = 0; n0 < N; n0 += per){
      int n1 = n0 + per; if (n1 > N) n1 = N;
      attn4_k<<<(n1 - n0 + 3) / 4, 256, 0, stream>>>(Q1, Q2, Q3, Q4, KVall,
                                                     row_off, esrc, cat_h, cat_sv, n0, n1);
    }
  }

  // ---- paired post-attn chain (h-branch = y0, sv-branch = y1) ----
  {
    GPairArgs A = {};
    A.X[0] = cat_h;  A.W[0] = Wob;  A.bias[0] = bo;   A.resb[0] = h_f;  A.gatep[0] = nullptr;
    A.outb[0] = Xb1; A.stats_out[0] = stats;
    A.X[1] = cat_sv; A.W[1] = Wohb; A.bias[1] = bo_h; A.resb[1] = sv_f; A.gatep[1] = Gbuf;
    A.outb[1] = Q1;  A.stats_out[1] = stats + 512;
    gemm_pair_k<256,128,3,4,0,1,256><<<dim3(GB, 2), 256, 0, stream>>>(A, N, invN);
  }
  {
    GPairArgs A = {};
    A.X[0] = Xb1; A.W[0] = W1b;  A.bias[0] = b1;
    A.astats[0] = stats;       A.ag[0] = gbn1;  A.ab[0] = bbn1;  A.outb[0] = cat_h;
    A.X[1] = Q1;  A.W[1] = W1hb; A.bias[1] = b1h;
    A.astats[1] = stats + 512; A.ag[1] = gbn1h; A.ab[1] = bbn1h; A.outb[1] = cat_sv;
    gemm_pair_k<128,256,1,1,1,0,256><<<dim3(GB, 2), 256, 0, stream>>>(A, N, invN);
  }
  {
    GPairArgs A = {};
    A.X[0] = cat_h;  A.W[0] = W2b;  A.bias[0] = b2;  A.resb[0] = Xb1;
    A.rstats[0] = stats;       A.rg[0] = gbn1;  A.rb[0] = bbn1;
    A.outb[0] = Xb2; A.stats_out[0] = stats + 256;
    A.X[1] = cat_sv; A.W[1] = W2hb; A.bias[1] = b2h; A.resb[1] = Q1;  A.gatep[1] = Gbuf + 128;
    A.rstats[1] = stats + 512; A.rg[1] = gbn1h; A.rb[1] = bbn1h;
    A.outb[1] = Q2;  A.stats_out[1] = stats + 768;
    gemm_pair_k<256,128,5,6,0,1,256><<<dim3(GB, 2), 256, 0, stream>>>(A, N, invN);
  }
  {
    Bn2Args A;
    A.x[0] = Xb2; A.stats[0] = stats + 256; A.g[0] = gbn2;  A.b[0] = bbn2;  A.out[0] = out_h;
    A.x[1] = Q2;  A.stats[1] = stats + 768; A.g[1] = gbn2h; A.b[1] = bbn2h; A.out[1] = out_sv;
    bn2_k<<<dim3(APB, 2), 256, 0, stream>>>(A, T4, invN);
  }
}

// Round 12
// 699.962 us; speedup vs baseline: 1.0369x; 1.0369x over previous
//
#include <hip/hip_runtime.h>

typedef _Float16 f16x8 __attribute__((ext_vector_type(8)));
typedef _Float16 f16x2 __attribute__((ext_vector_type(2)));
typedef __fp16 fp16x2_raw __attribute__((ext_vector_type(2)));
typedef float f32x4 __attribute__((ext_vector_type(4)));
typedef float f32x2 __attribute__((ext_vector_type(2)));
typedef unsigned int uint32;
typedef unsigned short ushort16;
typedef unsigned char uchar;

#define EPS_BN 1e-5f

__device__ __forceinline__ uint32 pk16(float a, float b){
  fp16x2_raw h = __builtin_amdgcn_cvt_pkrtz(a, b);
  return *(uint32*)&h;
}
__device__ __forceinline__ uchar f2fp8(float f){
  uint32 p = __builtin_amdgcn_cvt_pk_fp8_f32(f, f, 0, false);
  return (uchar)(p & 0xff);
}
__device__ __forceinline__ f32x2 fp8pair_lo(uint32 w){
  return __builtin_amdgcn_cvt_pk_f32_fp8(w, false);
}
__device__ __forceinline__ f32x2 fp8pair_hi(uint32 w){
  return __builtin_amdgcn_cvt_pk_f32_fp8(w, true);
}

// ---------------- weight conversion table ----------------
struct WEnt { const float* s; const float* s2; ushort16* d; int KD, MD, nfrag; };
struct WConv { WEnt e[16]; };

// ---------------- conv f32->f16 for h/sv ----------------
__global__ __launch_bounds__(256) void conv2_k(const float* __restrict__ a, const float* __restrict__ b,
                                               ushort16* __restrict__ da, ushort16* __restrict__ db, int n){
  const float* s = blockIdx.y ? b : a;
  ushort16* d = blockIdx.y ? db : da;
  int i = (blockIdx.x * 256 + threadIdx.x) * 4;
  if (i >= n) return;
  float4 v = *(const float4*)(s + i);
  uint2 p;
  p.x = pk16(v.x, v.y);
  p.y = pk16(v.z, v.w);
  *(uint2*)(d + i) = p;
}

// ---------------- aux: bucket-count (x<512) + conv_w (x>=512) ----------------
__global__ __launch_bounds__(256) void aux_k(WConv wc,
    const int* __restrict__ dst, int* __restrict__ bcnt, int E, int shift){
  int bx = blockIdx.x;
  if (bx < 512){
    __shared__ int lh[128];
    int tid = threadIdx.x;
    if (tid < 128) lh[tid] = 0;
    __syncthreads();
    int stride = 512 * 256;
    for (int i = bx * 256 + tid; i < E; i += stride)
      atomicAdd(&lh[dst[i] >> shift], 1);
    __syncthreads();
    if (tid < 128 && lh[tid]) atomicAdd(&bcnt[tid], lh[tid]);
  } else {
    int b = bx - 512;
    WEnt t = wc.e[b >> 4];
    int fid = (b & 15) * 256 + threadIdx.x;
    if (fid >= t.nfrag) return;
    int lane = fid & 63, sm = fid >> 6;
    int MT = t.MD >> 4;
    int s = sm / MT, m = sm - s * MT;
    int row = m * 16 + (lane & 15);
    int col = s * 32 + (lane >> 4) * 8;
    const float* sp = t.s;
    if (t.s2 && row >= 128){ sp = t.s2; row -= 128; }
    const float* p = sp + (size_t)row * t.KD + col;
    uint4 o;
    o.x = pk16(p[0], p[1]); o.y = pk16(p[2], p[3]);
    o.z = pk16(p[4], p[5]); o.w = pk16(p[6], p[7]);
    *(uint4*)(t.d + (size_t)fid * 8) = o;
  }
}

// ---------------- bucket prefix (tiny) ----------------
__global__ __launch_bounds__(64) void bscan_k(const int* __restrict__ bcnt,
    int* __restrict__ bstart, int* __restrict__ bcur, int B){
  if (threadIdx.x == 0){
    int run = 0;
    for (int b = 0; b < B; b++){ bstart[b] = run; bcur[b] = run; run += bcnt[b]; }
    bstart[B] = run;
  }
}

// ---------------- bucketed grouping: LDS-binned by dst bucket ----------------
#define BIN_TB 512
#define BIN_TILE 4096
__global__ __launch_bounds__(512) void bin_k(const int* __restrict__ src, const int* __restrict__ dst,
                                             int* __restrict__ bcur, uint2* __restrict__ ebuf,
                                             int E, int shift, int B){
  __shared__ int lhist[128];
  __shared__ int lstart[128];
  __shared__ int gbase[128];
  __shared__ uint2 lpair[BIN_TILE];
  int tid = threadIdx.x;
  int base = blockIdx.x * BIN_TILE;
  int cnt = E - base; if (cnt > BIN_TILE) cnt = BIN_TILE;
  if (tid < 128) lhist[tid] = 0;
  __syncthreads();
  int myb[8], myrank[8];
  uint2 myp[8];
  int nmine = 0;
  #pragma unroll
  for (int j = 0; j < 8; j++){
    int i = tid + j * BIN_TB;
    if (i < cnt){
      int s = src[base + i], d = dst[base + i];
      int b = d >> shift;
      myp[nmine] = make_uint2((uint32)s, (uint32)d);
      myb[nmine] = b;
      myrank[nmine] = atomicAdd(&lhist[b], 1);
      nmine++;
    }
  }
  __syncthreads();
  if (tid == 0){
    int run = 0;
    for (int b = 0; b < B; b++){ lstart[b] = run; run += lhist[b]; }
  }
  __syncthreads();
  if (tid < B) gbase[tid] = atomicAdd(&bcur[tid], lhist[tid]);
  for (int j = 0; j < nmine; j++){
    lpair[lstart[myb[j]] + myrank[j]] = myp[j];
  }
  __syncthreads();
  for (int i = tid; i < cnt; i += BIN_TB){
    uint2 p = lpair[i];
    int b = (int)(p.y >> shift);
    ebuf[gbase[b] + (i - lstart[b])] = p;
  }
}

// ---------------- per-bucket CSR finalize: row_off + esrc, LDS-atomic only ----------------
#define CSR_TB 1024
__global__ __launch_bounds__(1024) void csr_k(const uint2* __restrict__ ebuf,
    const int* __restrict__ bstart, int* __restrict__ row_off, int* __restrict__ esrc,
    int shift, int N, int E, int B){
  __shared__ int lc[4096];
  __shared__ int lcur[4096];
  __shared__ int wsum[16];
  int b = blockIdx.x;
  int d0 = b << shift;
  int nd = 1 << shift; if (d0 + nd > N) nd = N - d0;
  if (nd <= 0) return;
  int e0 = bstart[b], e1 = bstart[b + 1];
  int tid = threadIdx.x, lane = tid & 63, wv = tid >> 6;
  for (int j = tid; j < nd; j += CSR_TB){ lc[j] = 0; lcur[j] = 0; }
  __syncthreads();
  // pass 1: per-dst counts (LDS atomics)
  for (int i = e0 + tid; i < e1; i += CSR_TB){
    atomicAdd(&lc[(int)ebuf[i].y - d0], 1);
  }
  __syncthreads();
  // block exclusive scan of lc[0..nd), 4 elements per thread
  int base4 = tid * 4;
  int v0 = (base4 + 0 < nd) ? lc[base4 + 0] : 0;
  int v1 = (base4 + 1 < nd) ? lc[base4 + 1] : 0;
  int v2 = (base4 + 2 < nd) ? lc[base4 + 2] : 0;
  int v3 = (base4 + 3 < nd) ? lc[base4 + 3] : 0;
  int ts = v0 + v1 + v2 + v3;
  int inc = ts;
  #pragma unroll
  for (int d = 1; d < 64; d <<= 1){
    int t = __shfl_up(inc, d);
    if (lane >= d) inc += t;
  }
  if (lane == 63) wsum[wv] = inc;
  __syncthreads();
  int woff = 0;
  for (int w = 0; w < 16; w++) if (w < wv) woff += wsum[w];
  int excl = woff + (inc - ts);
  int o0 = excl, o1 = o0 + v0, o2 = o1 + v1, o3 = o2 + v2;
  __syncthreads();   // all reads of lc done before overwrite
  if (base4 + 0 < nd){ lc[base4 + 0] = o0; row_off[d0 + base4 + 0] = e0 + o0; }
  if (base4 + 1 < nd){ lc[base4 + 1] = o1; row_off[d0 + base4 + 1] = e0 + o1; }
  if (base4 + 2 < nd){ lc[base4 + 2] = o2; row_off[d0 + base4 + 2] = e0 + o2; }
  if (base4 + 3 < nd){ lc[base4 + 3] = o3; row_off[d0 + base4 + 3] = e0 + o3; }
  __syncthreads();
  // pass 2: rank-scatter esrc (LDS cursor atomics only)
  for (int i = e0 + tid; i < e1; i += CSR_TB){
    uint2 p = ebuf[i];
    int d = (int)p.y - d0;
    int r = atomicAdd(&lcur[d], 1);
    esrc[e0 + lc[d] + r] = (int)p.x;
  }
  if (b == B - 1 && tid == 0) row_off[N] = E;
}

// ---------------- generic GEMM body, block-LDS-staged weights, f16 in/out ----------------
// W (64 KB) staged into LDS in two 32 KB halves (once per BLOCK, not per wave:
// 4x L2 traffic cut). The 32 KB stage buffer is reused as the Os output-staging
// region after a barrier. MFMA order identical to the unstaged version.
// EPI: 1=relu, 2=sigmoid, 3=+res(f16), 4=gate w/ res(f16), 5=+BN(res), 6=gate w/ BN(res)
template<int KD, int MD, int EPI, int ABN, int ST, int GS>
__device__ __forceinline__ void gemm_body(
    const ushort16* __restrict__ X, const ushort16* __restrict__ W,
    const float* __restrict__ bias, const float* __restrict__ bias2,
    const ushort16* __restrict__ resb, const ushort16* __restrict__ gatep,
    const float* __restrict__ rstats, const float* __restrict__ rg, const float* __restrict__ rb,
    const float* __restrict__ astats, const float* __restrict__ ag, const float* __restrict__ ab,
    ushort16* __restrict__ outb, float* __restrict__ stats_out, int N, float invN,
    char* smem, float* sstB, float* sst2B)
{
  constexpr int KS = KD / 32;
  constexpr int MT = MD / 16;
  constexpr int KSH = KS / 2;
  constexpr int LSTR = MD + 8;
  int tid = threadIdx.x;
  int lane = tid & 63, wv = tid >> 6;
  _Float16* OsW = (_Float16*)smem + wv * 16 * LSTR;
  int l15 = lane & 15, kq = lane >> 4;
  int rowbase = (blockIdx.x * 4 + wv) * 16;
  int row = rowbase + l15;
  int rc = row < N ? row : N - 1;
  const f16x8* ap = (const f16x8*)(X + (size_t)rc * KD + kq * 8);
  f16x8 a[KS];
  #pragma unroll
  for (int s = 0; s < KS; s++) a[s] = ap[s * 4];
  if constexpr (ABN){
    #pragma unroll
    for (int s = 0; s < KS; s++){
      #pragma unroll
      for (int j = 0; j < 8; j++){
        int c = s * 32 + kq * 8 + j;
        float mm = astats[c] * invN;
        float var = astats[128 + c] * invN - mm * mm;
        float rs = rsqrtf(var + EPS_BN);
        float scc = rs * ag[c];
        float shh = ab[c] - mm * scc;
        a[s][j] = (_Float16)((float)a[s][j] * scc + shh);
      }
    }
  }
  const uint4* Wg4 = (const uint4*)W;
  uint4* Wl4 = (uint4*)smem;
  const f16x8* Wl8 = (const f16x8*)smem;
  f32x4 acc[MT];
  #pragma unroll
  for (int m = 0; m < MT; m++) acc[m] = (f32x4)(0.f);
  // ---- half 0: stage 32 KB of W, MFMA s in [0, KSH) ----
  {
    uint4 wb[8];
    #pragma unroll
    for (int r = 0; r < 8; r++) wb[r] = Wg4[tid + r * 256];
    #pragma unroll
    for (int r = 0; r < 8; r++) Wl4[tid + r * 256] = wb[r];
  }
  __syncthreads();
  #pragma unroll
  for (int s = 0; s < KSH; s++){
    #pragma unroll
    for (int m = 0; m < MT; m++){
      acc[m] = __builtin_amdgcn_mfma_f32_16x16x32_f16(a[s], Wl8[(s * MT + m) * 64 + lane], acc[m], 0, 0, 0);
    }
  }
  __syncthreads();
  // ---- half 1 ----
  {
    uint4 wb[8];
    #pragma unroll
    for (int r = 0; r < 8; r++) wb[r] = Wg4[2048 + tid + r * 256];
    #pragma unroll
    for (int r = 0; r < 8; r++) Wl4[tid + r * 256] = wb[r];
  }
  __syncthreads();
  #pragma unroll
  for (int s = KSH; s < KS; s++){
    #pragma unroll
    for (int m = 0; m < MT; m++){
      acc[m] = __builtin_amdgcn_mfma_f32_16x16x32_f16(a[s], Wl8[((s - KSH) * MT + m) * 64 + lane], acc[m], 0, 0, 0);
    }
  }
  __syncthreads();   // all waves done reading Wl; smem becomes Os
  float ps[MT], ps2[MT];
  if constexpr (ST){
    #pragma unroll
    for (int m = 0; m < MT; m++){ ps[m] = 0.f; ps2[m] = 0.f; }
  }
  int r0 = rowbase + kq * 4;
  #pragma unroll
  for (int m = 0; m < MT; m++){
    int col = m * 16 + l15;
    float bv;
    if (bias2 && col >= 128) bv = bias2[col - 128];
    else bv = bias[col];
    float sc = 0.f, sh = 0.f;
    if constexpr (EPI == 5 || EPI == 6){
      float mm = rstats[col] * invN;
      float var = rstats[128 + col] * invN - mm * mm;
      float rs = rsqrtf(var + EPS_BN);
      sc = rs * rg[col]; sh = rb[col] - mm * sc;
    }
    #pragma unroll
    for (int r = 0; r < 4; r++){
      int rr = r0 + r;
      float v;
      {
        int rrc = rr < N ? rr : N - 1;
        v = acc[m][r] + bv;
        if constexpr (EPI == 1) v = fmaxf(v, 0.f);
        if constexpr (EPI == 2) v = 1.f / (1.f + __expf(-v));
        if constexpr (EPI == 3){
          union { ushort16 u; _Float16 h; } cv; cv.u = resb[(size_t)rrc * 128 + col];
          v += (float)cv.h;
        }
        if constexpr (EPI == 5){
          union { ushort16 u; _Float16 h; } cv; cv.u = resb[(size_t)rrc * 128 + col];
          v += (float)cv.h * sc + sh;
        }
        if constexpr (EPI == 4 || EPI == 6){
          union { ushort16 u; _Float16 h; } gv; gv.u = gatep[(size_t)rrc * GS + col];
          union { ushort16 u; _Float16 h; } cv; cv.u = resb[(size_t)rrc * 128 + col];
          float g = (float)gv.h;
          float rv = (float)cv.h;
          if constexpr (EPI == 6) rv = rv * sc + sh;
          v = (1.f - g) * rv + g * v;
        }
      }
      OsW[(kq * 4 + r) * LSTR + col] = (_Float16)v;
      if constexpr (ST){
        if (rr < N){ ps[m] += v; ps2[m] += v * v; }
      }
    }
  }
  if constexpr (MD == 128){
    #pragma unroll
    for (int p = 0; p < 4; p++){
      int lrow = p * 4 + (lane >> 4);
      int rr = rowbase + lrow;
      int col8 = l15 * 8;
      if (rr < N){
        uint4 ov = *(uint4*)&OsW[lrow * LSTR + col8];
        *(uint4*)(outb + (size_t)rr * MD + col8) = ov;
      }
    }
  } else {
    #pragma unroll
    for (int p = 0; p < 8; p++){
      int lrow = p * 2 + (lane >> 5);
      int rr = rowbase + lrow;
      int col8 = (lane & 31) * 8;
      if (rr < N){
        uint4 ov = *(uint4*)&OsW[lrow * LSTR + col8];
        *(uint4*)(outb + (size_t)rr * MD + col8) = ov;
      }
    }
  }
  if constexpr (ST){
    #pragma unroll
    for (int m = 0; m < MT; m++){
      float s = ps[m], s2 = ps2[m];
      s  += __shfl_xor(s, 16);  s  += __shfl_xor(s, 32);
      s2 += __shfl_xor(s2, 16); s2 += __shfl_xor(s2, 32);
      if (lane < 16){ sstB[wv * 128 + m * 16 + l15] = s; sst2B[wv * 128 + m * 16 + l15] = s2; }
    }
    __syncthreads();
    if (tid < 128){
      atomicAdd(&stats_out[tid], sstB[tid] + sstB[128 + tid] + sstB[256 + tid] + sstB[384 + tid]);
    } else {
      int c = tid - 128;
      atomicAdd(&stats_out[tid], sst2B[c] + sst2B[128 + c] + sst2B[256 + c] + sst2B[384 + c]);
    }
  }
}

// shared-buffer size: max(32 KB weight stage, Os region)
template<int MD>
struct SmemSz { static constexpr int v = (32768 > 4 * 16 * (MD + 8) * 2) ? 32768 : 4 * 16 * (MD + 8) * 2; };

// single-config GEMM kernel (used for the gate projection)
template<int KD, int MD, int EPI, int ABN, int ST, int GS>
__global__ __launch_bounds__(256) void gemm_k(
    const ushort16* __restrict__ X, const ushort16* __restrict__ W,
    const float* __restrict__ bias, const float* __restrict__ bias2,
    const ushort16* __restrict__ resb, const ushort16* __restrict__ gatep,
    const float* __restrict__ rstats, const float* __restrict__ rg, const float* __restrict__ rb,
    const float* __restrict__ astats, const float* __restrict__ ag, const float* __restrict__ ab,
    ushort16* __restrict__ outb, float* __restrict__ stats_out, int N, float invN)
{
  __shared__ char smem[SmemSz<MD>::v];
  __shared__ float sst[512];
  __shared__ float sst2[512];
  gemm_body<KD, MD, EPI, ABN, ST, GS>(X, W, bias, bias2, resb, gatep, rstats, rg, rb,
                                      astats, ag, ab, outb, stats_out, N, invN, smem, sst, sst2);
}

// ---------------- QKV projection x4 slots: block-level LDS weight staging ----------------
struct QkvArgs {
  const ushort16* Xq[4];
  const ushort16* Xkv[4];
  const ushort16* Wq[4];
  const ushort16* Wk[4];
  const ushort16* Wv[4];
  ushort16* Qo[4];
};
__global__ __launch_bounds__(256) void qkv_k(QkvArgs A, uchar* __restrict__ KV8, int N)
{
  __shared__ _Float16 Wl[16384];        // 32 KB staged weight matrix
  __shared__ _Float16 S[4][16 * 136];   // 17.4 KB per-wave stage-out
  int slot = blockIdx.y;
  int toff = slot << 8;
  const ushort16* Xq = A.Xq[slot];
  const ushort16* Xkv = A.Xkv[slot];
  ushort16* Qo = A.Qo[slot];
  int tid = threadIdx.x;
  int lane = tid & 63, wv = tid >> 6;
  _Float16* SW = S[wv];
  uchar* SB = (uchar*)SW;
  int l15 = lane & 15, kq = lane >> 4;
  int rowbase = (blockIdx.x * 4 + wv) * 16;
  int row = rowbase + l15;
  int rc = row < N ? row : N - 1;
  const f16x8* aq = (const f16x8*)(Xq + (size_t)rc * 128 + kq * 8);
  const f16x8* ak = (const f16x8*)(Xkv + (size_t)rc * 128 + kq * 8);
  f16x8 Aq[4], Ak[4];
  #pragma unroll
  for (int s = 0; s < 4; s++){ Aq[s] = aq[s * 4]; Ak[s] = ak[s * 4]; }
  const uint4* Wq4 = (const uint4*)A.Wq[slot];
  const uint4* Wk4 = (const uint4*)A.Wk[slot];
  const uint4* Wv4 = (const uint4*)A.Wv[slot];
  uint4* Wl4 = (uint4*)Wl;
  const f16x8* Wl8 = (const f16x8*)Wl;
  f32x4 acc[8];

  // ---- stage Q ----
  {
    uint4 wb[8];
    #pragma unroll
    for (int r = 0; r < 8; r++) wb[r] = Wq4[tid + r * 256];
    #pragma unroll
    for (int r = 0; r < 8; r++) Wl4[tid + r * 256] = wb[r];
  }
  __syncthreads();
  #pragma unroll
  for (int m = 0; m < 8; m++) acc[m] = (f32x4)(0.f);
  #pragma unroll
  for (int s = 0; s < 4; s++){
    #pragma unroll
    for (int m = 0; m < 8; m++){
      acc[m] = __builtin_amdgcn_mfma_f32_16x16x32_f16(Aq[s], Wl8[(s * 8 + m) * 64 + lane], acc[m], 0, 0, 0);
    }
  }
  #pragma unroll
  for (int m = 0; m < 8; m++){
    int col = m * 16 + l15;
    #pragma unroll
    for (int r = 0; r < 4; r++)
      SW[(kq * 4 + r) * 136 + col] = (_Float16)acc[m][r];
  }
  #pragma unroll
  for (int p = 0; p < 4; p++){
    int lrow = p * 4 + kq;
    int rr = rowbase + lrow;
    int col8 = l15 * 8;
    if (rr < N){
      uint4 qv = *(uint4*)&SW[lrow * 136 + col8];
      *(uint4*)(Qo + (size_t)rr * 128 + col8) = qv;
    }
  }
  __syncthreads();   // all waves done reading Wl before overwrite

  // ---- stage K ----
  {
    uint4 wb[8];
    #pragma unroll
    for (int r = 0; r < 8; r++) wb[r] = Wk4[tid + r * 256];
    #pragma unroll
    for (int r = 0; r < 8; r++) Wl4[tid + r * 256] = wb[r];
  }
  __syncthreads();
  #pragma unroll
  for (int m = 0; m < 8; m++) acc[m] = (f32x4)(0.f);
  #pragma unroll
  for (int s = 0; s < 4; s++){
    #pragma unroll
    for (int m = 0; m < 8; m++){
      acc[m] = __builtin_amdgcn_mfma_f32_16x16x32_f16(Ak[s], Wl8[(s * 8 + m) * 64 + lane], acc[m], 0, 0, 0);
    }
  }
  #pragma unroll
  for (int m = 0; m < 8; m++){
    int col = m * 16 + l15;
    #pragma unroll
    for (int r = 0; r < 4; r++)
      SB[(kq * 4 + r) * 136 + col] = f2fp8(acc[m][r]);
  }
  #pragma unroll
  for (int p = 0; p < 4; p++){
    int lrow = p * 4 + kq;
    int rr = rowbase + lrow;
    int col8 = l15 * 8;
    if (rr < N){
      uint2 kv = *(uint2*)&SB[lrow * 136 + col8];
      *(uint2*)(KV8 + (size_t)rr * 1024 + toff + col8) = kv;
    }
  }
  __syncthreads();

  // ---- stage V ----
  {
    uint4 wb[8];
    #pragma unroll
    for (int r = 0; r < 8; r++) wb[r] = Wv4[tid + r * 256];
    #pragma unroll
    for (int r = 0; r < 8; r++) Wl4[tid + r * 256] = wb[r];
  }
  __syncthreads();
  #pragma unroll
  for (int m = 0; m < 8; m++) acc[m] = (f32x4)(0.f);
  #pragma unroll
  for (int s = 0; s < 4; s++){
    #pragma unroll
    for (int m = 0; m < 8; m++){
      acc[m] = __builtin_amdgcn_mfma_f32_16x16x32_f16(Ak[s], Wl8[(s * 8 + m) * 64 + lane], acc[m], 0, 0, 0);
    }
  }
  #pragma unroll
  for (int m = 0; m < 8; m++){
    int col = m * 16 + l15;
    #pragma unroll
    for (int r = 0; r < 4; r++)
      SB[(kq * 4 + r) * 136 + col] = f2fp8(acc[m][r]);
  }
  #pragma unroll
  for (int p = 0; p < 4; p++){
    int lrow = p * 4 + kq;
    int rr = rowbase + lrow;
    int col8 = l15 * 8;
    if (rr < N){
      uint2 vv = *(uint2*)&SB[lrow * 136 + col8];
      *(uint2*)(KV8 + (size_t)rr * 1024 + toff + 128 + col8) = vv;
    }
  }
}

// paired GEMM kernel: blockIdx.y selects config (h-branch / sv-branch), shapes identical
struct GPairArgs {
  const ushort16* X[2]; const ushort16* W[2];
  const float* bias[2];
  const ushort16* resb[2]; const ushort16* gatep[2];
  const float* rstats[2]; const float* rg[2]; const float* rb[2];
  const float* astats[2]; const float* ag[2]; const float* ab[2];
  ushort16* outb[2]; float* stats_out[2];
};
template<int KD, int MD, int EPI0, int EPI1, int ABN, int ST, int GS>
__global__ __launch_bounds__(256) void gemm_pair_k(GPairArgs A, int N, float invN)
{
  __shared__ char smem[SmemSz<MD>::v];
  __shared__ float sst[512];
  __shared__ float sst2[512];
  int y = blockIdx.y;
  if (y == 0){
    gemm_body<KD, MD, EPI0, ABN, ST, GS>(A.X[0], A.W[0], A.bias[0], nullptr, A.resb[0], A.gatep[0],
        A.rstats[0], A.rg[0], A.rb[0], A.astats[0], A.ag[0], A.ab[0],
        A.outb[0], A.stats_out[0], N, invN, smem, sst, sst2);
  } else {
    gemm_body<KD, MD, EPI1, ABN, ST, GS>(A.X[1], A.W[1], A.bias[1], nullptr, A.resb[1], A.gatep[1],
        A.rstats[1], A.rg[1], A.rb[1], A.astats[1], A.ag[1], A.ab[1],
        A.outb[1], A.stats_out[1], N, invN, smem, sst, sst2);
  }
}

// ---------------- fused QUAD attention, 16 lanes/edge, interleaved KV pool ----------------
// BW-walled on the random-gather path (~3.8 TB/s); frozen since r3. Single dispatch.
__global__ __launch_bounds__(256) void attn4_k(
    const ushort16* __restrict__ Qa, const ushort16* __restrict__ Qb,
    const ushort16* __restrict__ Qc, const ushort16* __restrict__ Qd,
    const uchar* __restrict__ KV,
    const int* __restrict__ row_off, const int* __restrict__ esrc,
    ushort16* __restrict__ cat_h, ushort16* __restrict__ cat_sv, int n0, int n1)
{
  int wv = threadIdx.x >> 6, lane = threadIdx.x & 63;
  int n = n0 + blockIdx.x * 4 + wv;
  if (n >= n1) return;
  int g = lane >> 4, j = lane & 15;      // 4 edge slots x 16 lanes
  uint32 j8 = (uint32)j * 8u;            // 8 fp8 elems per lane
  const float QS = 0.25f * 1.44269504088896f; // 1/sqrt(DH) * log2(e)
  const float CL = 7.21347520444482f;          // 5 * log2(e)
  const ushort16* Qp[4] = {Qa, Qb, Qc, Qd};
  f32x2 q[4][4];
  #pragma unroll
  for (int t = 0; t < 4; t++){
    uint4 u = *(const uint4*)(Qp[t] + (size_t)n * 128 + j8);
    f16x2 h0 = *(f16x2*)&u.x, h1 = *(f16x2*)&u.y;
    f16x2 h2 = *(f16x2*)&u.z, h3 = *(f16x2*)&u.w;
    q[t][0].x = (float)h0.x * QS; q[t][0].y = (float)h0.y * QS;
    q[t][1].x = (float)h1.x * QS; q[t][1].y = (float)h1.y * QS;
    q[t][2].x = (float)h2.x * QS; q[t][2].y = (float)h2.y * QS;
    q[t][3].x = (float)h3.x * QS; q[t][3].y = (float)h3.y * QS;
  }
  int e0 = row_off[n], e1 = row_off[n + 1];
  int itmax = (e1 - e0 + 3) >> 2;
  f32x2 ac[4][4];
  #pragma unroll
  for (int t = 0; t < 4; t++){
    #pragma unroll
    for (int r = 0; r < 4; r++) ac[t][r] = (f32x2)(0.f);
  }
  float z[4] = {0.f, 0.f, 0.f, 0.f};
  int e = e0 + g;
  int s = (e < e1) ? esrc[e] : -1;
  uint32 off = ((uint32)(s < 0 ? 0 : s) << 10) + j8;
  uint2 kc[4], vc[4];
  #pragma unroll
  for (int t = 0; t < 4; t++){
    kc[t] = *(const uint2*)(KV + off + t * 256);
    vc[t] = *(const uint2*)(KV + off + t * 256 + 128);
  }
  for (int it = 0; it < itmax; ++it){
    int e2 = e + 4;
    int s2 = (e2 < e1) ? esrc[e2] : -1;
    uint32 off2 = ((uint32)(s2 < 0 ? 0 : s2) << 10) + j8;
    uint2 kn[4], vn[4];
    #pragma unroll
    for (int t = 0; t < 4; t++){
      kn[t] = *(const uint2*)(KV + off2 + t * 256);
      vn[t] = *(const uint2*)(KV + off2 + t * 256 + 128);
    }
    if (s >= 0){
      #pragma unroll
      for (int t = 0; t < 4; t++){
        f32x2 k0 = fp8pair_lo(kc[t].x), k1 = fp8pair_hi(kc[t].x);
        f32x2 k2 = fp8pair_lo(kc[t].y), k3 = fp8pair_hi(kc[t].y);
        f32x2 dd = k0 * q[t][0] + k1 * q[t][1] + k2 * q[t][2] + k3 * q[t][3];
        float d = dd.x + dd.y;
        d += __shfl_xor(d, 1);   // lanes j, j^1 cover one 16-elem head
        float sc = __builtin_amdgcn_exp2f(__builtin_amdgcn_fmed3f(d, -CL, CL));
        f32x2 v0 = fp8pair_lo(vc[t].x), v1 = fp8pair_hi(vc[t].x);
        f32x2 v2 = fp8pair_lo(vc[t].y), v3 = fp8pair_hi(vc[t].y);
        f32x2 sv; sv.x = sc; sv.y = sc;
        ac[t][0] += sv * v0; ac[t][1] += sv * v1;
        ac[t][2] += sv * v2; ac[t][3] += sv * v3;
        z[t] += sc;
      }
    }
    e = e2; s = s2; off = off2;
    #pragma unroll
    for (int t = 0; t < 4; t++){ kc[t] = kn[t]; vc[t] = vn[t]; }
  }
  // reduce across the 4 edge slots (lanes differing in bits 4,5)
  #pragma unroll
  for (int t = 0; t < 4; t++){
    #pragma unroll
    for (int r = 0; r < 4; r++){
      ac[t][r].x += __shfl_xor(ac[t][r].x, 16);
      ac[t][r].y += __shfl_xor(ac[t][r].y, 16);
      ac[t][r].x += __shfl_xor(ac[t][r].x, 32);
      ac[t][r].y += __shfl_xor(ac[t][r].y, 32);
    }
    z[t] += __shfl_xor(z[t], 16);
    z[t] += __shfl_xor(z[t], 32);
  }
  if (g == 0){
    size_t base = (size_t)n * 256 + j8;
    #pragma unroll
    for (int t = 0; t < 4; t++){
      float rz = __builtin_amdgcn_rcpf(z[t]);
      uint4 o;
      o.x = pk16(ac[t][0].x * rz, ac[t][0].y * rz);
      o.y = pk16(ac[t][1].x * rz, ac[t][1].y * rz);
      o.z = pk16(ac[t][2].x * rz, ac[t][2].y * rz);
      o.w = pk16(ac[t][3].x * rz, ac[t][3].y * rz);
      ushort16* dp = (t < 2) ? cat_h : cat_sv;
      *(uint4*)(dp + base + (t & 1) * 128) = o;
    }
  }
}

// ---------------- BatchNorm apply pair (f16 in, f32 out) ----------------
struct Bn2Args {
  const ushort16* x[2]; const float* stats[2];
  const float* g[2]; const float* b[2]; float* out[2];
};
__global__ __launch_bounds__(256) void bn2_k(Bn2Args A, int total4, float invN)
{
  int y = blockIdx.y;
  int i = blockIdx.x * 256 + threadIdx.x;
  if (i >= total4) return;
  const ushort16* x = A.x[y];
  const float* stats = A.stats[y];
  const float* gamma = A.g[y];
  const float* beta = A.b[y];
  float* outf = A.out[y];
  uint2 xp = *(const uint2*)(x + (size_t)i * 4);
  f16x2 x01 = *(f16x2*)&xp.x, x23 = *(f16x2*)&xp.y;
  float xv[4] = {(float)x01.x, (float)x01.y, (float)x23.x, (float)x23.y};
  int c0 = (i * 4) & 127;
  float o[4];
  #pragma unroll
  for (int j = 0; j < 4; j++){
    int c = c0 + j;
    float m = stats[c] * invN;
    float var = stats[128 + c] * invN - m * m;
    float rstd = rsqrtf(var + EPS_BN);
    o[j] = (xv[j] - m) * rstd * gamma[c] + beta[c];
  }
  *(float4*)(outf + (size_t)i * 4) = make_float4(o[0], o[1], o[2], o[3]);
}

// ---------------- host ----------------
extern "C" void kernel_launch(void* const* d_in, const int* in_sizes, int n_in,
                              void* d_out, int out_size, void* d_ws, size_t ws_size,
                              hipStream_t stream) {
  const float* h   = (const float*)d_in[0];
  const float* sv  = (const float*)d_in[1];
  const int* src   = (const int*)d_in[2];
  const int* dst   = (const int*)d_in[3];
  const int N = in_sizes[0] / 128;
  const int E = in_sizes[2];

  char* wsb = (char*)d_ws;
  size_t o = 0;
  auto take = [&](size_t bytes)->size_t{
    size_t r = o;
    o = (o + bytes + 255) & ~(size_t)255;
    return r;
  };
  // shared big region: ebuf (CSR build) -> KV pool (attention)
  size_t big = (size_t)E * 8;
  if (big < (size_t)N * 1024) big = (size_t)N * 1024;
  size_t bcnt_off   = take(128 * 4);             // zeroed
  size_t stats_off  = take(4 * 256 * 4);         // zeroed
  size_t bstart_off = take(132 * 4);
  size_t bcur_off   = take(128 * 4);
  size_t rowoff_off = take((size_t)(N + 1) * 4);
  size_t esrc_off   = take((size_t)E * 4);
  size_t big_off    = take(big);
  size_t wpool_off  = take((size_t)376832 * 2);
  size_t hf_off     = take((size_t)N * 128 * 2);
  size_t svf_off    = take((size_t)N * 128 * 2);
  size_t cath_off   = take((size_t)N * 256 * 2);
  size_t catsv_off  = take((size_t)N * 256 * 2);
  size_t Q1_off     = take((size_t)N * 128 * 2);
  size_t Q2_off     = take((size_t)N * 128 * 2);
  size_t X1_off     = take((size_t)N * 128 * 2);
  size_t X2_off     = take((size_t)N * 128 * 2);
  size_t G_off      = take((size_t)N * 256 * 2);   // dedicated gate buffer (pre-attn)

  int*    bcnt    = (int*)(wsb + bcnt_off);
  float*  stats   = (float*)(wsb + stats_off);
  int*    bstart  = (int*)(wsb + bstart_off);
  int*    bcur    = (int*)(wsb + bcur_off);
  int*    row_off = (int*)(wsb + rowoff_off);
  int*    esrc    = (int*)(wsb + esrc_off);
  uint2*  ebuf    = (uint2*)(wsb + big_off);     // dead after csr_k
  uchar*  KVall   = (uchar*)(wsb + big_off);     // live qkv..attn4
  ushort16* wpool = (ushort16*)(wsb + wpool_off);
  ushort16* h_f   = (ushort16*)(wsb + hf_off);
  ushort16* sv_f  = (ushort16*)(wsb + svf_off);
  ushort16* cat_h = (ushort16*)(wsb + cath_off);
  ushort16* cat_sv= (ushort16*)(wsb + catsv_off);
  ushort16* Q1    = (ushort16*)(wsb + Q1_off);
  ushort16* Q2    = (ushort16*)(wsb + Q2_off);
  ushort16* Xb1   = (ushort16*)(wsb + X1_off);
  ushort16* Xb2   = (ushort16*)(wsb + X2_off);
  ushort16* Gbuf  = (ushort16*)(wsb + G_off);
  ushort16* Q3 = Xb1;                     // X1/X2 written only after attention
  ushort16* Q4 = Xb2;

  ushort16* Wq_sv = wpool + 0 * 16384;
  ushort16* Wk_sv = wpool + 1 * 16384;
  ushort16* Wv_sv = wpool + 2 * 16384;
  ushort16* Wq_cv = wpool + 3 * 16384;
  ushort16* Wk_cv = wpool + 4 * 16384;
  ushort16* Wv_cv = wpool + 5 * 16384;
  ushort16* Wq_sh = wpool + 6 * 16384;
  ushort16* Wk_sh = wpool + 7 * 16384;
  ushort16* Wv_sh = wpool + 8 * 16384;
  ushort16* Wgb   = wpool + 147456;
  ushort16* Wob   = wpool + 180224;
  ushort16* Wohb  = wpool + 212992;
  ushort16* W1b   = wpool + 245760;
  ushort16* W2b   = wpool + 278528;
  ushort16* W1hb  = wpool + 311296;
  ushort16* W2hb  = wpool + 344064;

  const float* bo   = (const float*)d_in[14];
  const float* bo_h = (const float*)d_in[16];
  const float* b1   = (const float*)d_in[18];
  const float* b2   = (const float*)d_in[20];
  const float* b1h  = (const float*)d_in[22];
  const float* b2h  = (const float*)d_in[24];
  const float* bg1  = (const float*)d_in[26];
  const float* bg2  = (const float*)d_in[28];
  const float* gbn1  = (const float*)d_in[29];
  const float* bbn1  = (const float*)d_in[30];
  const float* gbn2  = (const float*)d_in[31];
  const float* bbn2  = (const float*)d_in[32];
  const float* gbn1h = (const float*)d_in[33];
  const float* bbn1h = (const float*)d_in[34];
  const float* gbn2h = (const float*)d_in[35];
  const float* bbn2h = (const float*)d_in[36];

  float* out_h  = (float*)d_out;
  float* out_sv = out_h + (size_t)N * 128;

  (void)hipMemsetAsync(wsb, 0, stats_off + 4 * 256 * 4, stream);

  WConv wc;
  {
    auto set = [&](int i, int din, int din2, size_t dstoff, int KD, int MD){
      wc.e[i].s  = (const float*)d_in[din];
      wc.e[i].s2 = (din2 >= 0) ? (const float*)d_in[din2] : nullptr;
      wc.e[i].d  = wpool + dstoff;
      wc.e[i].KD = KD; wc.e[i].MD = MD;
      wc.e[i].nfrag = KD * MD / 8;
    };
    for (int i = 0; i < 9; i++) set(i, 4 + i, -1, (size_t)i * 16384, 128, 128);
    set(9,  25, 27, 147456, 128, 256);
    set(10, 13, -1, 180224, 256, 128);
    set(11, 15, -1, 212992, 256, 128);
    set(12, 17, -1, 245760, 128, 256);
    set(13, 19, -1, 278528, 256, 128);
    set(14, 21, -1, 311296, 128, 256);
    set(15, 23, -1, 344064, 256, 128);
  }

  // bucket params: B <= 128 buckets of 2^shift dst values
  int shift = 9;
  while ((((N - 1) >> shift) + 1) > 128) shift++;
  const int B = ((N - 1) >> shift) + 1;

  int nelem = N * 128;
  int CVB = (nelem / 4 + 255) / 256;
  // conv h/sv (right-sized) + aux (bucket-count 512 blocks, conv_w 256 blocks)
  conv2_k<<<dim3(CVB, 2), 256, 0, stream>>>(h, sv, h_f, sv_f, nelem);
  aux_k<<<768, 256, 0, stream>>>(wc, dst, bcnt, E, shift);

  bscan_k<<<1, 64, 0, stream>>>(bcnt, bstart, bcur, B);
  bin_k<<<(E + BIN_TILE - 1) / BIN_TILE, BIN_TB, 0, stream>>>(src, dst, bcur, ebuf, E, shift, B);
  csr_k<<<B, CSR_TB, 0, stream>>>(ebuf, bstart, row_off, esrc, shift, N, E, B);

  const int GB = (N + 63) / 64;
  const int AB = (N + 3) / 4;
  const int T4 = nelem / 4;
  const int APB = (T4 + 255) / 256;
  const float invN = 1.f / (float)N;

  // gate projection (own dispatch; LDS-staged weights via gemm_body)
  gemm_k<128,256,2,0,0,256><<<GB, 256, 0, stream>>>(h_f, Wgb, bg1, bg2, nullptr, nullptr,
      nullptr, nullptr, nullptr, nullptr, nullptr, nullptr, Gbuf, nullptr, N, invN);

  // four QKV projections (LDS-staged weights), then single quad-attention
  QkvArgs qa;
  qa.Xq[0] = h_f;  qa.Xkv[0] = h_f;  qa.Wq[0] = Wq_sv; qa.Wk[0] = Wk_sv; qa.Wv[0] = Wv_sv; qa.Qo[0] = Q1;
  qa.Xq[1] = h_f;  qa.Xkv[1] = sv_f; qa.Wq[1] = Wq_cv; qa.Wk[1] = Wk_cv; qa.Wv[1] = Wv_cv; qa.Qo[1] = Q2;
  qa.Xq[2] = sv_f; qa.Xkv[2] = sv_f; qa.Wq[2] = Wq_sh; qa.Wk[2] = Wk_sh; qa.Wv[2] = Wv_sh; qa.Qo[2] = Q3;
  qa.Xq[3] = sv_f; qa.Xkv[3] = h_f;  qa.Wq[3] = Wq_cv; qa.Wk[3] = Wk_cv; qa.Wv[3] = Wv_cv; qa.Qo[3] = Q4;
  qkv_k<<<dim3(GB, 4), 256, 0, stream>>>(qa, KVall, N);
  attn4_k<<<AB, 256, 0, stream>>>(Q1, Q2, Q3, Q4, KVall, row_off, esrc, cat_h, cat_sv, 0, N);

  // ---- paired post-attn chain (h-branch = y0, sv-branch = y1) ----
  {
    GPairArgs A = {};
    A.X[0] = cat_h;  A.W[0] = Wob;  A.bias[0] = bo;   A.resb[0] = h_f;  A.gatep[0] = nullptr;
    A.outb[0] = Xb1; A.stats_out[0] = stats;
    A.X[1] = cat_sv; A.W[1] = Wohb; A.bias[1] = bo_h; A.resb[1] = sv_f; A.gatep[1] = Gbuf;
    A.outb[1] = Q1;  A.stats_out[1] = stats + 512;
    gemm_pair_k<256,128,3,4,0,1,256><<<dim3(GB, 2), 256, 0, stream>>>(A, N, invN);
  }
  {
    GPairArgs A = {};
    A.X[0] = Xb1; A.W[0] = W1b;  A.bias[0] = b1;
    A.astats[0] = stats;       A.ag[0] = gbn1;  A.ab[0] = bbn1;  A.outb[0] = cat_h;
    A.X[1] = Q1;  A.W[1] = W1hb; A.bias[1] = b1h;
    A.astats[1] = stats + 512; A.ag[1] = gbn1h; A.ab[1] = bbn1h; A.outb[1] = cat_sv;
    gemm_pair_k<128,256,1,1,1,0,256><<<dim3(GB, 2), 256, 0, stream>>>(A, N, invN);
  }
  {
    GPairArgs A = {};
    A.X[0] = cat_h;  A.W[0] = W2b;  A.bias[0] = b2;  A.resb[0] = Xb1;
    A.rstats[0] = stats;       A.rg[0] = gbn1;  A.rb[0] = bbn1;
    A.outb[0] = Xb2; A.stats_out[0] = stats + 256;
    A.X[1] = cat_sv; A.W[1] = W2hb; A.bias[1] = b2h; A.resb[1] = Q1;  A.gatep[1] = Gbuf + 128;
    A.rstats[1] = stats + 512; A.rg[1] = gbn1h; A.rb[1] = bbn1h;
    A.outb[1] = Q2;  A.stats_out[1] = stats + 768;
    gemm_pair_k<256,128,5,6,0,1,256><<<dim3(GB, 2), 256, 0, stream>>>(A, N, invN);
  }
  {
    Bn2Args A;
    A.x[0] = Xb2; A.stats[0] = stats + 256; A.g[0] = gbn2;  A.b[0] = bbn2;  A.out[0] = out_h;
    A.x[1] = Q2;  A.stats[1] = stats + 768; A.g[1] = gbn2h; A.b[1] = bbn2h; A.out[1] = out_sv;
    bn2_k<<<dim3(APB, 2), 256, 0, stream>>>(A, T4, invN);
  }
}